// Round 16
// baseline (187.237 us; speedup 1.0000x reference)
//
#include <hip/hip_runtime.h>
#include <hip/hip_fp16.h>
#include <cstdint>

// ---------------------------------------------------------------------------
// 2-layer GCN, zero scattered global atomics, per-node CSR gather.
// Gather tables (xsc, xs2) are fp16 [N,16] = 3.2 MB (L2-resident).
// Gathers: 4 nodes per wave (avg degree 32), lane = grp(4)x slot(4)x quad(4).
// CSR build: hist/scan/place (4-way ILP) + single-kernel nodesort.
// BS=128 buckets -> 782 nodesort blocks (~3 blocks/CU, ~24 waves/CU).
// ---------------------------------------------------------------------------

#define BS 128          // nodes per bucket (CSR build)
#define CHUNKS 256      // edge chunks for hist/place

__device__ __forceinline__ int2 nt_load_edge(const int2* p) {
    long long v = __builtin_nontemporal_load((const long long*)p);
    int2 r;
    r.x = (int)(v & 0xFFFFFFFFll);
    r.y = (int)(v >> 32);
    return r;
}

// 4 fp16 -> 4 fp32 from an 8B-aligned half pointer
__device__ __forceinline__ float4 load_h4(const __half* p) {
    uint2 u = *(const uint2*)p;
    __half2 p0 = *(__half2*)&u.x;
    __half2 p1 = *(__half2*)&u.y;
    float2 f0 = __half22float2(p0);
    float2 f1 = __half22float2(p1);
    float4 r;
    r.x = f0.x; r.y = f0.y; r.z = f1.x; r.w = f1.y;
    return r;
}

__global__ __launch_bounds__(1024) void hist_kernel(
        const int* __restrict__ col, int* __restrict__ part,
        int E, int nbuck, int per) {
    extern __shared__ int sh[];
    for (int t = threadIdx.x; t < nbuck; t += blockDim.x) sh[t] = 0;
    __syncthreads();
    int lo = blockIdx.x * per, hi = min(E, lo + per);
    for (int e = lo + threadIdx.x; e < hi; e += blockDim.x)
        atomicAdd(&sh[col[e] >> 7], 1);
    __syncthreads();
    for (int t = threadIdx.x; t < nbuck; t += blockDim.x)
        part[(size_t)blockIdx.x * nbuck + t] = sh[t];
}

__global__ void colscan_kernel(const int* __restrict__ part, int* __restrict__ base,
                               int* __restrict__ tot, int nbuck) {
    int b = blockIdx.x;
    if (b >= nbuck) return;
    int lane = threadIdx.x;  // 64
    int off = 0;
    for (int g = 0; g < CHUNKS; g += 64) {
        int c = g + lane;
        int v = part[(size_t)c * nbuck + b];
        int s = v;
        #pragma unroll
        for (int d = 1; d < 64; d <<= 1) {
            int t = __shfl_up(s, d);
            if (lane >= d) s += t;
        }
        base[(size_t)c * nbuck + b] = off + (s - v);
        off += __shfl(s, 63);
    }
    if (lane == 0) tot[b] = off;
}

__global__ void scan1_kernel(const int* __restrict__ cnt, int* __restrict__ excl,
                             int* __restrict__ bsum, int n) {
    __shared__ int s[256];
    int tid = threadIdx.x;
    int i = blockIdx.x * 256 + tid;
    int v = (i < n) ? cnt[i] : 0;
    s[tid] = v;
    __syncthreads();
    for (int off = 1; off < 256; off <<= 1) {
        int t = (tid >= off) ? s[tid - off] : 0;
        __syncthreads();
        s[tid] += t;
        __syncthreads();
    }
    if (i < n) excl[i] = s[tid] - v;
    if (tid == 255) bsum[blockIdx.x] = s[255];
}

__global__ void scan2_kernel(int* __restrict__ bsum, int nb) {
    __shared__ int s[512];
    int tid = threadIdx.x;
    int v = (tid < nb) ? bsum[tid] : 0;
    s[tid] = v;
    __syncthreads();
    for (int off = 1; off < 512; off <<= 1) {
        int t = (tid >= off) ? s[tid - off] : 0;
        __syncthreads();
        s[tid] += t;
        __syncthreads();
    }
    if (tid < nb) bsum[tid] = s[tid] - v;
}

__global__ void scan3_kernel(int* __restrict__ excl, const int* __restrict__ bsum,
                             int n, int E) {
    int i = blockIdx.x * 256 + threadIdx.x;
    if (i < n) excl[i] += bsum[i >> 8];
    else if (i == n) excl[n] = E;
}

// 4-way ILP: 4 independent load->LDS-atomic->store chains in flight per thread
__global__ __launch_bounds__(1024) void place_kernel(
        const int* __restrict__ row, const int* __restrict__ col,
        const float* __restrict__ ew,
        const int* __restrict__ start, const int* __restrict__ base,
        int2* __restrict__ rw, int E, int nbuck, int per) {
    extern __shared__ int sh[];
    int* lbase = sh;          // nbuck
    int* cnt2  = sh + nbuck;  // nbuck
    int c = blockIdx.x;
    for (int t = threadIdx.x; t < nbuck; t += blockDim.x) {
        lbase[t] = start[t] + base[(size_t)c * nbuck + t];
        cnt2[t] = 0;
    }
    __syncthreads();
    int lo = c * per, hi = min(E, lo + per);
    const int stride = blockDim.x;
    int e = lo + threadIdx.x;
    for (; e + 3 * stride < hi; e += 4 * stride) {
        int cc[4], rr[4];
        float w[4];
#pragma unroll
        for (int k = 0; k < 4; ++k) {
            cc[k] = col[e + k * stride];
            rr[k] = row[e + k * stride];
            w[k]  = ew[e + k * stride];
        }
        int p[4];
#pragma unroll
        for (int k = 0; k < 4; ++k) {
            int b = cc[k] >> 7;
            p[k] = lbase[b] + atomicAdd(&cnt2[b], 1);
        }
#pragma unroll
        for (int k = 0; k < 4; ++k) {
            int2 v;
            v.x = rr[k] | ((cc[k] & 127) << 20);
            v.y = __float_as_int(w[k]);
            rw[p[k]] = v;
        }
    }
    for (; e < hi; e += stride) {
        int cc = col[e];
        int b = cc >> 7;
        int p = lbase[b] + atomicAdd(&cnt2[b], 1);
        int2 v;
        v.x = row[e] | ((cc & 127) << 20);
        v.y = __float_as_int(ew[e]);
        rw[p] = v;
    }
}

// per-bucket (128 nodes): counts -> LDS scan -> ptr, dis; node-sorted rw2
// rw2.x = row * 32 (byte offset into the fp16 [N,16] table). 4-way ILP.
__global__ __launch_bounds__(512) void nodesort_kernel(
        const int2* __restrict__ rw, const int* __restrict__ start,
        int2* __restrict__ rw2, int* __restrict__ ptr,
        float* __restrict__ dis, int N, int E, int nbuck) {
    __shared__ int cnt[BS];
    __shared__ float fdeg[BS];
    __shared__ int fill[BS];
    __shared__ int stmp[BS];
    int b = blockIdx.x, tid = threadIdx.x;
    if (tid < BS) { cnt[tid] = 0; fdeg[tid] = 0.f; }
    __syncthreads();
    int s0 = start[b], s1 = start[b + 1];

    // pass 1: count + weighted degree, 4-way unrolled
    {
        int e = s0 + tid;
        for (; e + 3 * 512 < s1; e += 4 * 512) {
            int2 v[4];
#pragma unroll
            for (int k = 0; k < 4; ++k) v[k] = rw[e + k * 512];
#pragma unroll
            for (int k = 0; k < 4; ++k) {
                int cl = v[k].x >> 20;
                atomicAdd(&cnt[cl], 1);
                atomicAdd(&fdeg[cl], __int_as_float(v[k].y));
            }
        }
        for (; e < s1; e += 512) {
            int2 v = rw[e];
            int cl = v.x >> 20;
            atomicAdd(&cnt[cl], 1);
            atomicAdd(&fdeg[cl], __int_as_float(v.y));
        }
    }
    __syncthreads();

    // Hillis-Steele inclusive scan of cnt[128] in LDS
    int myc = 0;
    if (tid < BS) { myc = cnt[tid]; stmp[tid] = myc; }
    __syncthreads();
    for (int off = 1; off < BS; off <<= 1) {
        int t = 0;
        if (tid < BS && tid >= off) t = stmp[tid - off];
        __syncthreads();
        if (tid < BS) stmp[tid] += t;
        __syncthreads();
    }
    if (tid < BS) {
        int excl = stmp[tid] - myc;
        ptr[b * BS + tid] = s0 + excl;
        fill[tid] = excl;
        int node = b * BS + tid;
        if (node < N) dis[node] = rsqrtf(fdeg[tid] + 1.0f);
    }
    __syncthreads();

    // pass 2: scatter to node-sorted order, 4-way unrolled
    {
        int e = s0 + tid;
        for (; e + 3 * 512 < s1; e += 4 * 512) {
            int2 v[4];
#pragma unroll
            for (int k = 0; k < 4; ++k) v[k] = rw[e + k * 512];
            int p[4];
#pragma unroll
            for (int k = 0; k < 4; ++k)
                p[k] = s0 + atomicAdd(&fill[v[k].x >> 20], 1);
#pragma unroll
            for (int k = 0; k < 4; ++k) {
                int2 o;
                o.x = (v[k].x & 0xFFFFF) << 5;   // byte offset = row * 32
                o.y = v[k].y;
                rw2[p[k]] = o;
            }
        }
        for (; e < s1; e += 512) {
            int2 v = rw[e];
            int p = s0 + atomicAdd(&fill[v.x >> 20], 1);
            int2 o;
            o.x = (v.x & 0xFFFFF) << 5;
            o.y = v.y;
            rw2[p] = o;
        }
    }
    if (b == 0 && tid == 0) ptr[nbuck * BS] = E;
}

// xsc = fp16(x * dis)
__global__ void xsc_kernel(const float* __restrict__ x, const float* __restrict__ dis,
                           __half* __restrict__ xsc, int N) {
    int i = blockIdx.x * 256 + threadIdx.x;
    if (i >= N) return;
    float d = dis[i];
    const float4* xr = (const float4*)(x + (size_t)i * 16);
    __half2 h[8];
#pragma unroll
    for (int k = 0; k < 4; ++k) {
        float4 v = xr[k];
        h[2*k]   = __floats2half2_rn(v.x * d, v.y * d);
        h[2*k+1] = __floats2half2_rn(v.z * d, v.w * d);
    }
    uint4* dst = (uint4*)(xsc + (size_t)i * 16);
    dst[0] = *(uint4*)&h[0];
    dst[1] = *(uint4*)&h[4];
}

// 4 nodes per wave: lane = grp(4) x slot(4) x quad(4).
// FINAL=0: dst = dis*(agg+self); FINAL=1: dst = dis*(agg+self)+b2.
template <int FINAL>
__global__ __launch_bounds__(256) void gather_kernel(
        const int* __restrict__ ptr, const int2* __restrict__ rw2,
        const __half* __restrict__ src, const float* __restrict__ dis,
        const float* __restrict__ b2, float* __restrict__ dst, int N) {
    int tid  = threadIdx.x;
    int wave = tid >> 6;
    int lane = tid & 63;
    int g = lane >> 4;            // node group within wave
    int s = (lane >> 2) & 3;      // 4 edge slots per node
    int q = lane & 3;             // 4 quads of 4 halves = 16 features
    int node = (blockIdx.x * 4 + wave) * 4 + g;
    if (node >= N) return;
    int s0 = ptr[node], s1 = ptr[node + 1];

    const char* srcb = (const char*)src;
    float4 a0 = {0.f, 0.f, 0.f, 0.f}, a1 = {0.f, 0.f, 0.f, 0.f};
    int e = s0 + s;
    for (; e + 4 < s1; e += 8) {               // 2-way unroll, stride 4/slot
        int2 v0 = nt_load_edge(&rw2[e]);
        int2 v1 = nt_load_edge(&rw2[e + 4]);
        float4 x0 = load_h4((const __half*)(srcb + v0.x) + q * 4);
        float4 x1 = load_h4((const __half*)(srcb + v1.x) + q * 4);
        float w0 = __int_as_float(v0.y), w1 = __int_as_float(v1.y);
        a0.x += w0 * x0.x; a0.y += w0 * x0.y; a0.z += w0 * x0.z; a0.w += w0 * x0.w;
        a1.x += w1 * x1.x; a1.y += w1 * x1.y; a1.z += w1 * x1.z; a1.w += w1 * x1.w;
    }
    if (e < s1) {
        int2 v0 = nt_load_edge(&rw2[e]);
        float4 x0 = load_h4((const __half*)(srcb + v0.x) + q * 4);
        float w0 = __int_as_float(v0.y);
        a0.x += w0 * x0.x; a0.y += w0 * x0.y; a0.z += w0 * x0.z; a0.w += w0 * x0.w;
    }
    a0.x += a1.x; a0.y += a1.y; a0.z += a1.z; a0.w += a1.w;
#pragma unroll
    for (int m = 4; m <= 8; m <<= 1) {         // reduce across 4 slots
        a0.x += __shfl_xor(a0.x, m);
        a0.y += __shfl_xor(a0.y, m);
        a0.z += __shfl_xor(a0.z, m);
        a0.w += __shfl_xor(a0.w, m);
    }

    if (s == 0) {
        float d = dis[node];
        float4 self = load_h4((const __half*)(srcb + ((size_t)node << 5)) + q * 4);
        float4 o;
        o.x = d * (a0.x + self.x);
        o.y = d * (a0.y + self.y);
        o.z = d * (a0.z + self.z);
        o.w = d * (a0.w + self.w);
        if (FINAL) {
            float4 bb = *(const float4*)(b2 + q * 4);
            o.x += bb.x; o.y += bb.y; o.z += bb.z; o.w += bb.w;
        }
        *(float4*)(dst + (size_t)node * 16 + q * 4) = o;
    }
}

// xs2 = fp16((relu(t @ W1^T + b1) @ W2^T) * dis), thread per node, regs only.
__global__ __launch_bounds__(256) void mlp_kernel(
        const float* __restrict__ t, const float* __restrict__ dis,
        const float* __restrict__ W1, const float* __restrict__ b1,
        const float* __restrict__ W2, __half* __restrict__ xs2, int N) {
    __shared__ float sW1[512];
    __shared__ float sW2[512];
    __shared__ float sb1[32];
    for (int k = threadIdx.x; k < 512; k += 256) {
        sW1[k] = W1[k];
        sW2[k] = W2[k];
    }
    if (threadIdx.x < 32) sb1[threadIdx.x] = b1[threadIdx.x];
    __syncthreads();
    int i = blockIdx.x * 256 + threadIdx.x;
    if (i >= N) return;

    float tr[16];
#pragma unroll
    for (int k = 0; k < 4; ++k) {
        float4 v = ((const float4*)(t + (size_t)i * 16))[k];
        tr[4*k+0] = v.x; tr[4*k+1] = v.y; tr[4*k+2] = v.z; tr[4*k+3] = v.w;
    }
    float h[32];
#pragma unroll
    for (int o = 0; o < 32; ++o) {
        float acc = sb1[o];
#pragma unroll
        for (int k = 0; k < 16; ++k) acc += tr[k] * sW1[o * 16 + k];
        h[o] = fmaxf(acc, 0.f);
    }
    float d = dis[i];
    float o16[16];
#pragma unroll
    for (int o = 0; o < 16; ++o) {
        float acc = 0.f;
#pragma unroll
        for (int k = 0; k < 32; ++k) acc += h[k] * sW2[o * 32 + k];
        o16[o] = acc * d;
    }
    __half2 hh[8];
#pragma unroll
    for (int k = 0; k < 8; ++k) hh[k] = __floats2half2_rn(o16[2*k], o16[2*k+1]);
    uint4* dst = (uint4*)(xs2 + (size_t)i * 16);
    dst[0] = *(uint4*)&hh[0];
    dst[1] = *(uint4*)&hh[4];
}

extern "C" void kernel_launch(void* const* d_in, const int* in_sizes, int n_in,
                              void* d_out, int out_size, void* d_ws, size_t ws_size,
                              hipStream_t stream) {
    const float* x  = (const float*)d_in[0];
    const int*   ei = (const int*)d_in[1];   // [2, E] int32
    const float* ew = (const float*)d_in[2];
    const float* W1 = (const float*)d_in[3];
    const float* b1 = (const float*)d_in[4];
    const float* W2 = (const float*)d_in[5];
    const float* b2 = (const float*)d_in[6];
    float* out = (float*)d_out;

    const int N = in_sizes[0] / 16;
    const int E = in_sizes[2];
    const int* row = ei;
    const int* col = ei + E;

    const int nbuck = (N + BS - 1) / BS;          // 782
    const int per   = (E + CHUNKS - 1) / CHUNKS;  // 12500
    const int nb    = (nbuck + 255) / 256;        // 4

    // workspace layout (4B units)
    //  [0, 2E)   : rw2 (node-sorted int2, .x = byte offset)
    //  [2E, 4E)  : rw (bucket-sorted int2), DEAD after nodesort; reused:
    //              xsc half[16N] (8N units) at 2E
    //              tbuf f32[16N] (16N units) at 2E+8N
    //              xs2 half[16N] (8N units) at 2E+24N      (32N <= 2E ok)
    //  [4E, ...) : dis[N], ptr[BS*nbuck+1], part, base, tot, start, bsum
    float*  ws    = (float*)d_ws;
    int2*   rw2   = (int2*)ws;
    int2*   rw    = (int2*)(ws + (size_t)2 * E);
    __half* xsc   = (__half*)(ws + (size_t)2 * E);
    float*  tbuf  = ws + (size_t)2 * E + (size_t)8 * N;
    __half* xs2   = (__half*)(ws + (size_t)2 * E + (size_t)24 * N);
    float*  dis   = ws + (size_t)4 * E;
    int*    ptr   = (int*)(dis + N);
    int*    part  = ptr + (size_t)BS * nbuck + 1;
    int*    base  = part + (size_t)CHUNKS * nbuck;
    int*    tot   = base + (size_t)CHUNKS * nbuck;
    int*    start = tot + nbuck;
    int*    bsum  = start + nbuck + 1;

    hist_kernel<<<CHUNKS, 1024, nbuck * 4, stream>>>(col, part, E, nbuck, per);
    colscan_kernel<<<nbuck, 64, 0, stream>>>(part, base, tot, nbuck);
    scan1_kernel<<<nb, 256, 0, stream>>>(tot, start, bsum, nbuck);
    scan2_kernel<<<1, 512, 0, stream>>>(bsum, nb);
    scan3_kernel<<<(nbuck + 256) / 256 + 1, 256, 0, stream>>>(start, bsum, nbuck, E);
    place_kernel<<<CHUNKS, 1024, 2 * nbuck * 4, stream>>>(row, col, ew, start, base, rw, E, nbuck, per);
    nodesort_kernel<<<nbuck, 512, 0, stream>>>(rw, start, rw2, ptr, dis, N, E, nbuck);

    xsc_kernel<<<(N + 255) / 256, 256, 0, stream>>>(x, dis, xsc, N);
    {
        int gblocks = (N + 15) / 16;   // 16 nodes per 256-thread block
        gather_kernel<0><<<gblocks, 256, 0, stream>>>(ptr, rw2, xsc, dis, b2, tbuf, N);
        mlp_kernel<<<(N + 255) / 256, 256, 0, stream>>>(tbuf, dis, W1, b1, W2, xs2, N);
        gather_kernel<1><<<gblocks, 256, 0, stream>>>(ptr, rw2, xs2, dis, b2, out, N);
    }
}

// Round 17
// 177.028 us; speedup vs baseline: 1.0577x; 1.0577x over previous
//
#include <hip/hip_runtime.h>
#include <hip/hip_fp16.h>
#include <cstdint>

// ---------------------------------------------------------------------------
// 2-layer GCN, zero scattered global atomics, per-node CSR gather.
// Gather tables (xsc, xs2) are fp16 [N,16] = 3.2 MB (L2-resident).
// Gathers: 4 nodes per wave (avg degree 32), lane = grp(4)x slot(4)x quad(4).
// CSR build: hist / colscan / single-block bucket scan / place (4-way ILP) /
// single-kernel nodesort. BS=256 (validated optimum for write coalescing).
// ---------------------------------------------------------------------------

#define BS 256          // nodes per bucket (CSR build)
#define CHUNKS 256      // edge chunks for hist/place

__device__ __forceinline__ int2 nt_load_edge(const int2* p) {
    long long v = __builtin_nontemporal_load((const long long*)p);
    int2 r;
    r.x = (int)(v & 0xFFFFFFFFll);
    r.y = (int)(v >> 32);
    return r;
}

// 4 fp16 -> 4 fp32 from an 8B-aligned half pointer
__device__ __forceinline__ float4 load_h4(const __half* p) {
    uint2 u = *(const uint2*)p;
    __half2 p0 = *(__half2*)&u.x;
    __half2 p1 = *(__half2*)&u.y;
    float2 f0 = __half22float2(p0);
    float2 f1 = __half22float2(p1);
    float4 r;
    r.x = f0.x; r.y = f0.y; r.z = f1.x; r.w = f1.y;
    return r;
}

__global__ __launch_bounds__(1024) void hist_kernel(
        const int* __restrict__ col, int* __restrict__ part,
        int E, int nbuck, int per) {
    extern __shared__ int sh[];
    for (int t = threadIdx.x; t < nbuck; t += blockDim.x) sh[t] = 0;
    __syncthreads();
    int lo = blockIdx.x * per, hi = min(E, lo + per);
    for (int e = lo + threadIdx.x; e < hi; e += blockDim.x)
        atomicAdd(&sh[col[e] >> 8], 1);
    __syncthreads();
    for (int t = threadIdx.x; t < nbuck; t += blockDim.x)
        part[(size_t)blockIdx.x * nbuck + t] = sh[t];
}

__global__ void colscan_kernel(const int* __restrict__ part, int* __restrict__ base,
                               int* __restrict__ tot, int nbuck) {
    int b = blockIdx.x;
    if (b >= nbuck) return;
    int lane = threadIdx.x;  // 64
    int off = 0;
    for (int g = 0; g < CHUNKS; g += 64) {
        int c = g + lane;
        int v = part[(size_t)c * nbuck + b];
        int s = v;
        #pragma unroll
        for (int d = 1; d < 64; d <<= 1) {
            int t = __shfl_up(s, d);
            if (lane >= d) s += t;
        }
        base[(size_t)c * nbuck + b] = off + (s - v);
        off += __shfl(s, 63);
    }
    if (lane == 0) tot[b] = off;
}

// single-block exclusive scan of tot[nbuck] -> start[nbuck+1] (nbuck <= 512)
__global__ void bscan_kernel(const int* __restrict__ tot, int* __restrict__ start,
                             int nbuck, int E) {
    __shared__ int s[512];
    int tid = threadIdx.x;
    int v = (tid < nbuck) ? tot[tid] : 0;
    s[tid] = v;
    __syncthreads();
    for (int off = 1; off < 512; off <<= 1) {
        int t = (tid >= off) ? s[tid - off] : 0;
        __syncthreads();
        s[tid] += t;
        __syncthreads();
    }
    if (tid < nbuck) start[tid] = s[tid] - v;
    if (tid == 0) start[nbuck] = E;
}

// 4-way ILP: 4 independent load->LDS-atomic->store chains in flight per thread
__global__ __launch_bounds__(1024) void place_kernel(
        const int* __restrict__ row, const int* __restrict__ col,
        const float* __restrict__ ew,
        const int* __restrict__ start, const int* __restrict__ base,
        int2* __restrict__ rw, int E, int nbuck, int per) {
    extern __shared__ int sh[];
    int* lbase = sh;          // nbuck
    int* cnt2  = sh + nbuck;  // nbuck
    int c = blockIdx.x;
    for (int t = threadIdx.x; t < nbuck; t += blockDim.x) {
        lbase[t] = start[t] + base[(size_t)c * nbuck + t];
        cnt2[t] = 0;
    }
    __syncthreads();
    int lo = c * per, hi = min(E, lo + per);
    const int stride = blockDim.x;
    int e = lo + threadIdx.x;
    for (; e + 3 * stride < hi; e += 4 * stride) {
        int cc[4], rr[4];
        float w[4];
#pragma unroll
        for (int k = 0; k < 4; ++k) {
            cc[k] = col[e + k * stride];
            rr[k] = row[e + k * stride];
            w[k]  = ew[e + k * stride];
        }
        int p[4];
#pragma unroll
        for (int k = 0; k < 4; ++k) {
            int b = cc[k] >> 8;
            p[k] = lbase[b] + atomicAdd(&cnt2[b], 1);
        }
#pragma unroll
        for (int k = 0; k < 4; ++k) {
            int2 v;
            v.x = rr[k] | ((cc[k] & 255) << 20);
            v.y = __float_as_int(w[k]);
            rw[p[k]] = v;
        }
    }
    for (; e < hi; e += stride) {
        int cc = col[e];
        int b = cc >> 8;
        int p = lbase[b] + atomicAdd(&cnt2[b], 1);
        int2 v;
        v.x = row[e] | ((cc & 255) << 20);
        v.y = __float_as_int(ew[e]);
        rw[p] = v;
    }
}

// per-bucket (256 nodes): counts -> LDS scan -> ptr, dis; node-sorted rw2
// rw2.x = row * 32 (byte offset into the fp16 [N,16] table). 4-way ILP.
__global__ __launch_bounds__(512) void nodesort_kernel(
        const int2* __restrict__ rw, const int* __restrict__ start,
        int2* __restrict__ rw2, int* __restrict__ ptr,
        float* __restrict__ dis, int N, int E, int nbuck) {
    __shared__ int cnt[BS];
    __shared__ float fdeg[BS];
    __shared__ int fill[BS];
    __shared__ int stmp[BS];
    int b = blockIdx.x, tid = threadIdx.x;
    for (int t = tid; t < BS; t += 512) { cnt[t] = 0; fdeg[t] = 0.f; }
    __syncthreads();
    int s0 = start[b], s1 = start[b + 1];

    // pass 1: count + weighted degree, 4-way unrolled
    {
        int e = s0 + tid;
        for (; e + 3 * 512 < s1; e += 4 * 512) {
            int2 v[4];
#pragma unroll
            for (int k = 0; k < 4; ++k) v[k] = rw[e + k * 512];
#pragma unroll
            for (int k = 0; k < 4; ++k) {
                int cl = v[k].x >> 20;
                atomicAdd(&cnt[cl], 1);
                atomicAdd(&fdeg[cl], __int_as_float(v[k].y));
            }
        }
        for (; e < s1; e += 512) {
            int2 v = rw[e];
            int cl = v.x >> 20;
            atomicAdd(&cnt[cl], 1);
            atomicAdd(&fdeg[cl], __int_as_float(v.y));
        }
    }
    __syncthreads();

    // Hillis-Steele inclusive scan of cnt[256] in LDS
    int myc = 0;
    if (tid < BS) { myc = cnt[tid]; stmp[tid] = myc; }
    __syncthreads();
    for (int off = 1; off < BS; off <<= 1) {
        int t = 0;
        if (tid < BS && tid >= off) t = stmp[tid - off];
        __syncthreads();
        if (tid < BS) stmp[tid] += t;
        __syncthreads();
    }
    if (tid < BS) {
        int excl = stmp[tid] - myc;
        ptr[b * BS + tid] = s0 + excl;
        fill[tid] = excl;
        int node = b * BS + tid;
        if (node < N) dis[node] = rsqrtf(fdeg[tid] + 1.0f);
    }
    __syncthreads();

    // pass 2: scatter to node-sorted order, 4-way unrolled
    {
        int e = s0 + tid;
        for (; e + 3 * 512 < s1; e += 4 * 512) {
            int2 v[4];
#pragma unroll
            for (int k = 0; k < 4; ++k) v[k] = rw[e + k * 512];
            int p[4];
#pragma unroll
            for (int k = 0; k < 4; ++k)
                p[k] = s0 + atomicAdd(&fill[v[k].x >> 20], 1);
#pragma unroll
            for (int k = 0; k < 4; ++k) {
                int2 o;
                o.x = (v[k].x & 0xFFFFF) << 5;   // byte offset = row * 32
                o.y = v[k].y;
                rw2[p[k]] = o;
            }
        }
        for (; e < s1; e += 512) {
            int2 v = rw[e];
            int p = s0 + atomicAdd(&fill[v.x >> 20], 1);
            int2 o;
            o.x = (v.x & 0xFFFFF) << 5;
            o.y = v.y;
            rw2[p] = o;
        }
    }
    if (b == 0 && tid == 0) ptr[nbuck * BS] = E;
}

// xsc = fp16(x * dis)
__global__ void xsc_kernel(const float* __restrict__ x, const float* __restrict__ dis,
                           __half* __restrict__ xsc, int N) {
    int i = blockIdx.x * 256 + threadIdx.x;
    if (i >= N) return;
    float d = dis[i];
    const float4* xr = (const float4*)(x + (size_t)i * 16);
    __half2 h[8];
#pragma unroll
    for (int k = 0; k < 4; ++k) {
        float4 v = xr[k];
        h[2*k]   = __floats2half2_rn(v.x * d, v.y * d);
        h[2*k+1] = __floats2half2_rn(v.z * d, v.w * d);
    }
    uint4* dst = (uint4*)(xsc + (size_t)i * 16);
    dst[0] = *(uint4*)&h[0];
    dst[1] = *(uint4*)&h[4];
}

// 4 nodes per wave: lane = grp(4) x slot(4) x quad(4).
// FINAL=0: dst = dis*(agg+self); FINAL=1: dst = dis*(agg+self)+b2.
template <int FINAL>
__global__ __launch_bounds__(256) void gather_kernel(
        const int* __restrict__ ptr, const int2* __restrict__ rw2,
        const __half* __restrict__ src, const float* __restrict__ dis,
        const float* __restrict__ b2, float* __restrict__ dst, int N) {
    int tid  = threadIdx.x;
    int wave = tid >> 6;
    int lane = tid & 63;
    int g = lane >> 4;            // node group within wave
    int s = (lane >> 2) & 3;      // 4 edge slots per node
    int q = lane & 3;             // 4 quads of 4 halves = 16 features
    int node = (blockIdx.x * 4 + wave) * 4 + g;
    if (node >= N) return;
    int s0 = ptr[node], s1 = ptr[node + 1];

    const char* srcb = (const char*)src;
    float4 a0 = {0.f, 0.f, 0.f, 0.f}, a1 = {0.f, 0.f, 0.f, 0.f};
    int e = s0 + s;
    for (; e + 4 < s1; e += 8) {               // 2-way unroll, stride 4/slot
        int2 v0 = nt_load_edge(&rw2[e]);
        int2 v1 = nt_load_edge(&rw2[e + 4]);
        float4 x0 = load_h4((const __half*)(srcb + v0.x) + q * 4);
        float4 x1 = load_h4((const __half*)(srcb + v1.x) + q * 4);
        float w0 = __int_as_float(v0.y), w1 = __int_as_float(v1.y);
        a0.x += w0 * x0.x; a0.y += w0 * x0.y; a0.z += w0 * x0.z; a0.w += w0 * x0.w;
        a1.x += w1 * x1.x; a1.y += w1 * x1.y; a1.z += w1 * x1.z; a1.w += w1 * x1.w;
    }
    if (e < s1) {
        int2 v0 = nt_load_edge(&rw2[e]);
        float4 x0 = load_h4((const __half*)(srcb + v0.x) + q * 4);
        float w0 = __int_as_float(v0.y);
        a0.x += w0 * x0.x; a0.y += w0 * x0.y; a0.z += w0 * x0.z; a0.w += w0 * x0.w;
    }
    a0.x += a1.x; a0.y += a1.y; a0.z += a1.z; a0.w += a1.w;
#pragma unroll
    for (int m = 4; m <= 8; m <<= 1) {         // reduce across 4 slots
        a0.x += __shfl_xor(a0.x, m);
        a0.y += __shfl_xor(a0.y, m);
        a0.z += __shfl_xor(a0.z, m);
        a0.w += __shfl_xor(a0.w, m);
    }

    if (s == 0) {
        float d = dis[node];
        float4 self = load_h4((const __half*)(srcb + ((size_t)node << 5)) + q * 4);
        float4 o;
        o.x = d * (a0.x + self.x);
        o.y = d * (a0.y + self.y);
        o.z = d * (a0.z + self.z);
        o.w = d * (a0.w + self.w);
        if (FINAL) {
            float4 bb = *(const float4*)(b2 + q * 4);
            o.x += bb.x; o.y += bb.y; o.z += bb.z; o.w += bb.w;
        }
        *(float4*)(dst + (size_t)node * 16 + q * 4) = o;
    }
}

// xs2 = fp16((relu(t @ W1^T + b1) @ W2^T) * dis), thread per node, regs only.
__global__ __launch_bounds__(256) void mlp_kernel(
        const float* __restrict__ t, const float* __restrict__ dis,
        const float* __restrict__ W1, const float* __restrict__ b1,
        const float* __restrict__ W2, __half* __restrict__ xs2, int N) {
    __shared__ float sW1[512];
    __shared__ float sW2[512];
    __shared__ float sb1[32];
    for (int k = threadIdx.x; k < 512; k += 256) {
        sW1[k] = W1[k];
        sW2[k] = W2[k];
    }
    if (threadIdx.x < 32) sb1[threadIdx.x] = b1[threadIdx.x];
    __syncthreads();
    int i = blockIdx.x * 256 + threadIdx.x;
    if (i >= N) return;

    float tr[16];
#pragma unroll
    for (int k = 0; k < 4; ++k) {
        float4 v = ((const float4*)(t + (size_t)i * 16))[k];
        tr[4*k+0] = v.x; tr[4*k+1] = v.y; tr[4*k+2] = v.z; tr[4*k+3] = v.w;
    }
    float h[32];
#pragma unroll
    for (int o = 0; o < 32; ++o) {
        float acc = sb1[o];
#pragma unroll
        for (int k = 0; k < 16; ++k) acc += tr[k] * sW1[o * 16 + k];
        h[o] = fmaxf(acc, 0.f);
    }
    float d = dis[i];
    float o16[16];
#pragma unroll
    for (int o = 0; o < 16; ++o) {
        float acc = 0.f;
#pragma unroll
        for (int k = 0; k < 32; ++k) acc += h[k] * sW2[o * 32 + k];
        o16[o] = acc * d;
    }
    __half2 hh[8];
#pragma unroll
    for (int k = 0; k < 8; ++k) hh[k] = __floats2half2_rn(o16[2*k], o16[2*k+1]);
    uint4* dst = (uint4*)(xs2 + (size_t)i * 16);
    dst[0] = *(uint4*)&hh[0];
    dst[1] = *(uint4*)&hh[4];
}

extern "C" void kernel_launch(void* const* d_in, const int* in_sizes, int n_in,
                              void* d_out, int out_size, void* d_ws, size_t ws_size,
                              hipStream_t stream) {
    const float* x  = (const float*)d_in[0];
    const int*   ei = (const int*)d_in[1];   // [2, E] int32
    const float* ew = (const float*)d_in[2];
    const float* W1 = (const float*)d_in[3];
    const float* b1 = (const float*)d_in[4];
    const float* W2 = (const float*)d_in[5];
    const float* b2 = (const float*)d_in[6];
    float* out = (float*)d_out;

    const int N = in_sizes[0] / 16;
    const int E = in_sizes[2];
    const int* row = ei;
    const int* col = ei + E;

    const int nbuck = (N + BS - 1) / BS;          // 391
    const int per   = (E + CHUNKS - 1) / CHUNKS;  // 12500

    // workspace layout (4B units)
    //  [0, 2E)   : rw2 (node-sorted int2, .x = byte offset)
    //  [2E, 4E)  : rw (bucket-sorted int2), DEAD after nodesort; reused:
    //              xsc half[16N] (8N units) at 2E
    //              tbuf f32[16N] (16N units) at 2E+8N
    //              xs2 half[16N] (8N units) at 2E+24N      (32N <= 2E ok)
    //  [4E, ...) : dis[N], ptr[BS*nbuck+1], part, base, tot, start
    float*  ws    = (float*)d_ws;
    int2*   rw2   = (int2*)ws;
    int2*   rw    = (int2*)(ws + (size_t)2 * E);
    __half* xsc   = (__half*)(ws + (size_t)2 * E);
    float*  tbuf  = ws + (size_t)2 * E + (size_t)8 * N;
    __half* xs2   = (__half*)(ws + (size_t)2 * E + (size_t)24 * N);
    float*  dis   = ws + (size_t)4 * E;
    int*    ptr   = (int*)(dis + N);
    int*    part  = ptr + (size_t)BS * nbuck + 1;
    int*    base  = part + (size_t)CHUNKS * nbuck;
    int*    tot   = base + (size_t)CHUNKS * nbuck;
    int*    start = tot + nbuck;

    hist_kernel<<<CHUNKS, 1024, nbuck * 4, stream>>>(col, part, E, nbuck, per);
    colscan_kernel<<<nbuck, 64, 0, stream>>>(part, base, tot, nbuck);
    bscan_kernel<<<1, 512, 0, stream>>>(tot, start, nbuck, E);
    place_kernel<<<CHUNKS, 1024, 2 * nbuck * 4, stream>>>(row, col, ew, start, base, rw, E, nbuck, per);
    nodesort_kernel<<<nbuck, 512, 0, stream>>>(rw, start, rw2, ptr, dis, N, E, nbuck);

    xsc_kernel<<<(N + 255) / 256, 256, 0, stream>>>(x, dis, xsc, N);
    {
        int gblocks = (N + 15) / 16;   // 16 nodes per 256-thread block
        gather_kernel<0><<<gblocks, 256, 0, stream>>>(ptr, rw2, xsc, dis, b2, tbuf, N);
        mlp_kernel<<<(N + 255) / 256, 256, 0, stream>>>(tbuf, dis, W1, b1, W2, xs2, N);
        gather_kernel<1><<<gblocks, 256, 0, stream>>>(ptr, rw2, xs2, dis, b2, out, N);
    }
}

// Round 18
// 175.133 us; speedup vs baseline: 1.0691x; 1.0108x over previous
//
#include <hip/hip_runtime.h>
#include <hip/hip_fp16.h>
#include <cstdint>

// ---------------------------------------------------------------------------
// 2-layer GCN, zero scattered global atomics, per-node CSR gather.
// Gather tables (xsc, xs2) are fp16 [N,16] = 3.2 MB (L2-resident).
// Gathers: 4 nodes per wave (avg degree 32), lane = grp(4)x slot(4)x quad(4).
// CSR build: hist / colscan / single-block bucket scan / place (4-way ILP) /
// single-kernel nodesort (1024 threads: ~24 waves/CU at 391 blocks).
// ---------------------------------------------------------------------------

#define BS 256          // nodes per bucket (CSR build)
#define CHUNKS 256      // edge chunks for hist/place
#define NST 1024        // nodesort threads per block

__device__ __forceinline__ int2 nt_load_edge(const int2* p) {
    long long v = __builtin_nontemporal_load((const long long*)p);
    int2 r;
    r.x = (int)(v & 0xFFFFFFFFll);
    r.y = (int)(v >> 32);
    return r;
}

// 4 fp16 -> 4 fp32 from an 8B-aligned half pointer
__device__ __forceinline__ float4 load_h4(const __half* p) {
    uint2 u = *(const uint2*)p;
    __half2 p0 = *(__half2*)&u.x;
    __half2 p1 = *(__half2*)&u.y;
    float2 f0 = __half22float2(p0);
    float2 f1 = __half22float2(p1);
    float4 r;
    r.x = f0.x; r.y = f0.y; r.z = f1.x; r.w = f1.y;
    return r;
}

__global__ __launch_bounds__(1024) void hist_kernel(
        const int* __restrict__ col, int* __restrict__ part,
        int E, int nbuck, int per) {
    extern __shared__ int sh[];
    for (int t = threadIdx.x; t < nbuck; t += blockDim.x) sh[t] = 0;
    __syncthreads();
    int lo = blockIdx.x * per, hi = min(E, lo + per);
    for (int e = lo + threadIdx.x; e < hi; e += blockDim.x)
        atomicAdd(&sh[col[e] >> 8], 1);
    __syncthreads();
    for (int t = threadIdx.x; t < nbuck; t += blockDim.x)
        part[(size_t)blockIdx.x * nbuck + t] = sh[t];
}

__global__ void colscan_kernel(const int* __restrict__ part, int* __restrict__ base,
                               int* __restrict__ tot, int nbuck) {
    int b = blockIdx.x;
    if (b >= nbuck) return;
    int lane = threadIdx.x;  // 64
    int off = 0;
    for (int g = 0; g < CHUNKS; g += 64) {
        int c = g + lane;
        int v = part[(size_t)c * nbuck + b];
        int s = v;
        #pragma unroll
        for (int d = 1; d < 64; d <<= 1) {
            int t = __shfl_up(s, d);
            if (lane >= d) s += t;
        }
        base[(size_t)c * nbuck + b] = off + (s - v);
        off += __shfl(s, 63);
    }
    if (lane == 0) tot[b] = off;
}

// single-block exclusive scan of tot[nbuck] -> start[nbuck+1] (nbuck <= 512)
__global__ void bscan_kernel(const int* __restrict__ tot, int* __restrict__ start,
                             int nbuck, int E) {
    __shared__ int s[512];
    int tid = threadIdx.x;
    int v = (tid < nbuck) ? tot[tid] : 0;
    s[tid] = v;
    __syncthreads();
    for (int off = 1; off < 512; off <<= 1) {
        int t = (tid >= off) ? s[tid - off] : 0;
        __syncthreads();
        s[tid] += t;
        __syncthreads();
    }
    if (tid < nbuck) start[tid] = s[tid] - v;
    if (tid == 0) start[nbuck] = E;
}

// 4-way ILP: 4 independent load->LDS-atomic->store chains in flight per thread
__global__ __launch_bounds__(1024) void place_kernel(
        const int* __restrict__ row, const int* __restrict__ col,
        const float* __restrict__ ew,
        const int* __restrict__ start, const int* __restrict__ base,
        int2* __restrict__ rw, int E, int nbuck, int per) {
    extern __shared__ int sh[];
    int* lbase = sh;          // nbuck
    int* cnt2  = sh + nbuck;  // nbuck
    int c = blockIdx.x;
    for (int t = threadIdx.x; t < nbuck; t += blockDim.x) {
        lbase[t] = start[t] + base[(size_t)c * nbuck + t];
        cnt2[t] = 0;
    }
    __syncthreads();
    int lo = c * per, hi = min(E, lo + per);
    const int stride = blockDim.x;
    int e = lo + threadIdx.x;
    for (; e + 3 * stride < hi; e += 4 * stride) {
        int cc[4], rr[4];
        float w[4];
#pragma unroll
        for (int k = 0; k < 4; ++k) {
            cc[k] = col[e + k * stride];
            rr[k] = row[e + k * stride];
            w[k]  = ew[e + k * stride];
        }
        int p[4];
#pragma unroll
        for (int k = 0; k < 4; ++k) {
            int b = cc[k] >> 8;
            p[k] = lbase[b] + atomicAdd(&cnt2[b], 1);
        }
#pragma unroll
        for (int k = 0; k < 4; ++k) {
            int2 v;
            v.x = rr[k] | ((cc[k] & 255) << 20);
            v.y = __float_as_int(w[k]);
            rw[p[k]] = v;
        }
    }
    for (; e < hi; e += stride) {
        int cc = col[e];
        int b = cc >> 8;
        int p = lbase[b] + atomicAdd(&cnt2[b], 1);
        int2 v;
        v.x = row[e] | ((cc & 255) << 20);
        v.y = __float_as_int(ew[e]);
        rw[p] = v;
    }
}

// per-bucket (256 nodes): counts -> LDS scan -> ptr, dis; node-sorted rw2
// rw2.x = row * 32 (byte offset into the fp16 [N,16] table). 1024 threads.
__global__ __launch_bounds__(NST) void nodesort_kernel(
        const int2* __restrict__ rw, const int* __restrict__ start,
        int2* __restrict__ rw2, int* __restrict__ ptr,
        float* __restrict__ dis, int N, int E, int nbuck) {
    __shared__ int cnt[BS];
    __shared__ float fdeg[BS];
    __shared__ int fill[BS];
    __shared__ int stmp[BS];
    int b = blockIdx.x, tid = threadIdx.x;
    if (tid < BS) { cnt[tid] = 0; fdeg[tid] = 0.f; }
    __syncthreads();
    int s0 = start[b], s1 = start[b + 1];

    // pass 1: count + weighted degree, 4-way unrolled
    {
        int e = s0 + tid;
        for (; e + 3 * NST < s1; e += 4 * NST) {
            int2 v[4];
#pragma unroll
            for (int k = 0; k < 4; ++k) v[k] = rw[e + k * NST];
#pragma unroll
            for (int k = 0; k < 4; ++k) {
                int cl = v[k].x >> 20;
                atomicAdd(&cnt[cl], 1);
                atomicAdd(&fdeg[cl], __int_as_float(v[k].y));
            }
        }
        for (; e < s1; e += NST) {
            int2 v = rw[e];
            int cl = v.x >> 20;
            atomicAdd(&cnt[cl], 1);
            atomicAdd(&fdeg[cl], __int_as_float(v.y));
        }
    }
    __syncthreads();

    // Hillis-Steele inclusive scan of cnt[256] in LDS
    int myc = 0;
    if (tid < BS) { myc = cnt[tid]; stmp[tid] = myc; }
    __syncthreads();
    for (int off = 1; off < BS; off <<= 1) {
        int t = 0;
        if (tid < BS && tid >= off) t = stmp[tid - off];
        __syncthreads();
        if (tid < BS) stmp[tid] += t;
        __syncthreads();
    }
    if (tid < BS) {
        int excl = stmp[tid] - myc;
        ptr[b * BS + tid] = s0 + excl;
        fill[tid] = excl;
        int node = b * BS + tid;
        if (node < N) dis[node] = rsqrtf(fdeg[tid] + 1.0f);
    }
    __syncthreads();

    // pass 2: scatter to node-sorted order, 4-way unrolled
    {
        int e = s0 + tid;
        for (; e + 3 * NST < s1; e += 4 * NST) {
            int2 v[4];
#pragma unroll
            for (int k = 0; k < 4; ++k) v[k] = rw[e + k * NST];
            int p[4];
#pragma unroll
            for (int k = 0; k < 4; ++k)
                p[k] = s0 + atomicAdd(&fill[v[k].x >> 20], 1);
#pragma unroll
            for (int k = 0; k < 4; ++k) {
                int2 o;
                o.x = (v[k].x & 0xFFFFF) << 5;   // byte offset = row * 32
                o.y = v[k].y;
                rw2[p[k]] = o;
            }
        }
        for (; e < s1; e += NST) {
            int2 v = rw[e];
            int p = s0 + atomicAdd(&fill[v.x >> 20], 1);
            int2 o;
            o.x = (v.x & 0xFFFFF) << 5;
            o.y = v.y;
            rw2[p] = o;
        }
    }
    if (b == 0 && tid == 0) ptr[nbuck * BS] = E;
}

// xsc = fp16(x * dis)
__global__ void xsc_kernel(const float* __restrict__ x, const float* __restrict__ dis,
                           __half* __restrict__ xsc, int N) {
    int i = blockIdx.x * 256 + threadIdx.x;
    if (i >= N) return;
    float d = dis[i];
    const float4* xr = (const float4*)(x + (size_t)i * 16);
    __half2 h[8];
#pragma unroll
    for (int k = 0; k < 4; ++k) {
        float4 v = xr[k];
        h[2*k]   = __floats2half2_rn(v.x * d, v.y * d);
        h[2*k+1] = __floats2half2_rn(v.z * d, v.w * d);
    }
    uint4* dst = (uint4*)(xsc + (size_t)i * 16);
    dst[0] = *(uint4*)&h[0];
    dst[1] = *(uint4*)&h[4];
}

// 4 nodes per wave: lane = grp(4) x slot(4) x quad(4).
// FINAL=0: dst = dis*(agg+self); FINAL=1: dst = dis*(agg+self)+b2.
template <int FINAL>
__global__ __launch_bounds__(256) void gather_kernel(
        const int* __restrict__ ptr, const int2* __restrict__ rw2,
        const __half* __restrict__ src, const float* __restrict__ dis,
        const float* __restrict__ b2, float* __restrict__ dst, int N) {
    int tid  = threadIdx.x;
    int wave = tid >> 6;
    int lane = tid & 63;
    int g = lane >> 4;            // node group within wave
    int s = (lane >> 2) & 3;      // 4 edge slots per node
    int q = lane & 3;             // 4 quads of 4 halves = 16 features
    int node = (blockIdx.x * 4 + wave) * 4 + g;
    if (node >= N) return;
    int s0 = ptr[node], s1 = ptr[node + 1];

    const char* srcb = (const char*)src;
    float4 a0 = {0.f, 0.f, 0.f, 0.f}, a1 = {0.f, 0.f, 0.f, 0.f};
    int e = s0 + s;
    for (; e + 4 < s1; e += 8) {               // 2-way unroll, stride 4/slot
        int2 v0 = nt_load_edge(&rw2[e]);
        int2 v1 = nt_load_edge(&rw2[e + 4]);
        float4 x0 = load_h4((const __half*)(srcb + v0.x) + q * 4);
        float4 x1 = load_h4((const __half*)(srcb + v1.x) + q * 4);
        float w0 = __int_as_float(v0.y), w1 = __int_as_float(v1.y);
        a0.x += w0 * x0.x; a0.y += w0 * x0.y; a0.z += w0 * x0.z; a0.w += w0 * x0.w;
        a1.x += w1 * x1.x; a1.y += w1 * x1.y; a1.z += w1 * x1.z; a1.w += w1 * x1.w;
    }
    if (e < s1) {
        int2 v0 = nt_load_edge(&rw2[e]);
        float4 x0 = load_h4((const __half*)(srcb + v0.x) + q * 4);
        float w0 = __int_as_float(v0.y);
        a0.x += w0 * x0.x; a0.y += w0 * x0.y; a0.z += w0 * x0.z; a0.w += w0 * x0.w;
    }
    a0.x += a1.x; a0.y += a1.y; a0.z += a1.z; a0.w += a1.w;
#pragma unroll
    for (int m = 4; m <= 8; m <<= 1) {         // reduce across 4 slots
        a0.x += __shfl_xor(a0.x, m);
        a0.y += __shfl_xor(a0.y, m);
        a0.z += __shfl_xor(a0.z, m);
        a0.w += __shfl_xor(a0.w, m);
    }

    if (s == 0) {
        float d = dis[node];
        float4 self = load_h4((const __half*)(srcb + ((size_t)node << 5)) + q * 4);
        float4 o;
        o.x = d * (a0.x + self.x);
        o.y = d * (a0.y + self.y);
        o.z = d * (a0.z + self.z);
        o.w = d * (a0.w + self.w);
        if (FINAL) {
            float4 bb = *(const float4*)(b2 + q * 4);
            o.x += bb.x; o.y += bb.y; o.z += bb.z; o.w += bb.w;
        }
        *(float4*)(dst + (size_t)node * 16 + q * 4) = o;
    }
}

// xs2 = fp16((relu(t @ W1^T + b1) @ W2^T) * dis), thread per node, regs only.
__global__ __launch_bounds__(256) void mlp_kernel(
        const float* __restrict__ t, const float* __restrict__ dis,
        const float* __restrict__ W1, const float* __restrict__ b1,
        const float* __restrict__ W2, __half* __restrict__ xs2, int N) {
    __shared__ float sW1[512];
    __shared__ float sW2[512];
    __shared__ float sb1[32];
    for (int k = threadIdx.x; k < 512; k += 256) {
        sW1[k] = W1[k];
        sW2[k] = W2[k];
    }
    if (threadIdx.x < 32) sb1[threadIdx.x] = b1[threadIdx.x];
    __syncthreads();
    int i = blockIdx.x * 256 + threadIdx.x;
    if (i >= N) return;

    float tr[16];
#pragma unroll
    for (int k = 0; k < 4; ++k) {
        float4 v = ((const float4*)(t + (size_t)i * 16))[k];
        tr[4*k+0] = v.x; tr[4*k+1] = v.y; tr[4*k+2] = v.z; tr[4*k+3] = v.w;
    }
    float h[32];
#pragma unroll
    for (int o = 0; o < 32; ++o) {
        float acc = sb1[o];
#pragma unroll
        for (int k = 0; k < 16; ++k) acc += tr[k] * sW1[o * 16 + k];
        h[o] = fmaxf(acc, 0.f);
    }
    float d = dis[i];
    float o16[16];
#pragma unroll
    for (int o = 0; o < 16; ++o) {
        float acc = 0.f;
#pragma unroll
        for (int k = 0; k < 32; ++k) acc += h[k] * sW2[o * 32 + k];
        o16[o] = acc * d;
    }
    __half2 hh[8];
#pragma unroll
    for (int k = 0; k < 8; ++k) hh[k] = __floats2half2_rn(o16[2*k], o16[2*k+1]);
    uint4* dst = (uint4*)(xs2 + (size_t)i * 16);
    dst[0] = *(uint4*)&hh[0];
    dst[1] = *(uint4*)&hh[4];
}

extern "C" void kernel_launch(void* const* d_in, const int* in_sizes, int n_in,
                              void* d_out, int out_size, void* d_ws, size_t ws_size,
                              hipStream_t stream) {
    const float* x  = (const float*)d_in[0];
    const int*   ei = (const int*)d_in[1];   // [2, E] int32
    const float* ew = (const float*)d_in[2];
    const float* W1 = (const float*)d_in[3];
    const float* b1 = (const float*)d_in[4];
    const float* W2 = (const float*)d_in[5];
    const float* b2 = (const float*)d_in[6];
    float* out = (float*)d_out;

    const int N = in_sizes[0] / 16;
    const int E = in_sizes[2];
    const int* row = ei;
    const int* col = ei + E;

    const int nbuck = (N + BS - 1) / BS;          // 391
    const int per   = (E + CHUNKS - 1) / CHUNKS;  // 12500

    // workspace layout (4B units)
    //  [0, 2E)   : rw2 (node-sorted int2, .x = byte offset)
    //  [2E, 4E)  : rw (bucket-sorted int2), DEAD after nodesort; reused:
    //              xsc half[16N] (8N units) at 2E
    //              tbuf f32[16N] (16N units) at 2E+8N
    //              xs2 half[16N] (8N units) at 2E+24N      (32N <= 2E ok)
    //  [4E, ...) : dis[N], ptr[BS*nbuck+1], part, base, tot, start
    float*  ws    = (float*)d_ws;
    int2*   rw2   = (int2*)ws;
    int2*   rw    = (int2*)(ws + (size_t)2 * E);
    __half* xsc   = (__half*)(ws + (size_t)2 * E);
    float*  tbuf  = ws + (size_t)2 * E + (size_t)8 * N;
    __half* xs2   = (__half*)(ws + (size_t)2 * E + (size_t)24 * N);
    float*  dis   = ws + (size_t)4 * E;
    int*    ptr   = (int*)(dis + N);
    int*    part  = ptr + (size_t)BS * nbuck + 1;
    int*    base  = part + (size_t)CHUNKS * nbuck;
    int*    tot   = base + (size_t)CHUNKS * nbuck;
    int*    start = tot + nbuck;

    hist_kernel<<<CHUNKS, 1024, nbuck * 4, stream>>>(col, part, E, nbuck, per);
    colscan_kernel<<<nbuck, 64, 0, stream>>>(part, base, tot, nbuck);
    bscan_kernel<<<1, 512, 0, stream>>>(tot, start, nbuck, E);
    place_kernel<<<CHUNKS, 1024, 2 * nbuck * 4, stream>>>(row, col, ew, start, base, rw, E, nbuck, per);
    nodesort_kernel<<<nbuck, NST, 0, stream>>>(rw, start, rw2, ptr, dis, N, E, nbuck);

    xsc_kernel<<<(N + 255) / 256, 256, 0, stream>>>(x, dis, xsc, N);
    {
        int gblocks = (N + 15) / 16;   // 16 nodes per 256-thread block
        gather_kernel<0><<<gblocks, 256, 0, stream>>>(ptr, rw2, xsc, dis, b2, tbuf, N);
        mlp_kernel<<<(N + 255) / 256, 256, 0, stream>>>(tbuf, dis, W1, b1, W2, xs2, N);
        gather_kernel<1><<<gblocks, 256, 0, stream>>>(ptr, rw2, xs2, dis, b2, out, N);
    }
}

// Round 19
// 162.436 us; speedup vs baseline: 1.1527x; 1.0782x over previous
//
#include <hip/hip_runtime.h>
#include <hip/hip_fp16.h>
#include <cstdint>

// ---------------------------------------------------------------------------
// 2-layer GCN, zero scattered global atomics, per-node CSR gather.
// Gather tables (xsc, xs2) are fp16 [N,16] = 3.2 MB (L2-resident).
// Gathers: 4 nodes per wave (avg degree 32), lane = grp(4)x slot(4)x quad(4).
// CSR build: hist / colscan / bscan / place (4-way ILP) / nodesort.
// nodesort pass 1 uses ONE 64-bit LDS atomic per edge (count<<40 | fx-deg),
// and the xsc (fp16 table build) is fused into nodesort's tail.
// ---------------------------------------------------------------------------

#define BS 256          // nodes per bucket (CSR build)
#define CHUNKS 256      // edge chunks for hist/place
#define NST 1024        // nodesort threads per block

__device__ __forceinline__ int2 nt_load_edge(const int2* p) {
    long long v = __builtin_nontemporal_load((const long long*)p);
    int2 r;
    r.x = (int)(v & 0xFFFFFFFFll);
    r.y = (int)(v >> 32);
    return r;
}

// 4 fp16 -> 4 fp32 from an 8B-aligned half pointer
__device__ __forceinline__ float4 load_h4(const __half* p) {
    uint2 u = *(const uint2*)p;
    __half2 p0 = *(__half2*)&u.x;
    __half2 p1 = *(__half2*)&u.y;
    float2 f0 = __half22float2(p0);
    float2 f1 = __half22float2(p1);
    float4 r;
    r.x = f0.x; r.y = f0.y; r.z = f1.x; r.w = f1.y;
    return r;
}

__global__ __launch_bounds__(1024) void hist_kernel(
        const int* __restrict__ col, int* __restrict__ part,
        int E, int nbuck, int per) {
    extern __shared__ int sh[];
    for (int t = threadIdx.x; t < nbuck; t += blockDim.x) sh[t] = 0;
    __syncthreads();
    int lo = blockIdx.x * per, hi = min(E, lo + per);
    for (int e = lo + threadIdx.x; e < hi; e += blockDim.x)
        atomicAdd(&sh[col[e] >> 8], 1);
    __syncthreads();
    for (int t = threadIdx.x; t < nbuck; t += blockDim.x)
        part[(size_t)blockIdx.x * nbuck + t] = sh[t];
}

__global__ void colscan_kernel(const int* __restrict__ part, int* __restrict__ base,
                               int* __restrict__ tot, int nbuck) {
    int b = blockIdx.x;
    if (b >= nbuck) return;
    int lane = threadIdx.x;  // 64
    int off = 0;
    for (int g = 0; g < CHUNKS; g += 64) {
        int c = g + lane;
        int v = part[(size_t)c * nbuck + b];
        int s = v;
        #pragma unroll
        for (int d = 1; d < 64; d <<= 1) {
            int t = __shfl_up(s, d);
            if (lane >= d) s += t;
        }
        base[(size_t)c * nbuck + b] = off + (s - v);
        off += __shfl(s, 63);
    }
    if (lane == 0) tot[b] = off;
}

// single-block exclusive scan of tot[nbuck] -> start[nbuck+1] (nbuck <= 512)
__global__ void bscan_kernel(const int* __restrict__ tot, int* __restrict__ start,
                             int nbuck, int E) {
    __shared__ int s[512];
    int tid = threadIdx.x;
    int v = (tid < nbuck) ? tot[tid] : 0;
    s[tid] = v;
    __syncthreads();
    for (int off = 1; off < 512; off <<= 1) {
        int t = (tid >= off) ? s[tid - off] : 0;
        __syncthreads();
        s[tid] += t;
        __syncthreads();
    }
    if (tid < nbuck) start[tid] = s[tid] - v;
    if (tid == 0) start[nbuck] = E;
}

// 4-way ILP: 4 independent load->LDS-atomic->store chains in flight per thread
__global__ __launch_bounds__(1024) void place_kernel(
        const int* __restrict__ row, const int* __restrict__ col,
        const float* __restrict__ ew,
        const int* __restrict__ start, const int* __restrict__ base,
        int2* __restrict__ rw, int E, int nbuck, int per) {
    extern __shared__ int sh[];
    int* lbase = sh;          // nbuck
    int* cnt2  = sh + nbuck;  // nbuck
    int c = blockIdx.x;
    for (int t = threadIdx.x; t < nbuck; t += blockDim.x) {
        lbase[t] = start[t] + base[(size_t)c * nbuck + t];
        cnt2[t] = 0;
    }
    __syncthreads();
    int lo = c * per, hi = min(E, lo + per);
    const int stride = blockDim.x;
    int e = lo + threadIdx.x;
    for (; e + 3 * stride < hi; e += 4 * stride) {
        int cc[4], rr[4];
        float w[4];
#pragma unroll
        for (int k = 0; k < 4; ++k) {
            cc[k] = col[e + k * stride];
            rr[k] = row[e + k * stride];
            w[k]  = ew[e + k * stride];
        }
        int p[4];
#pragma unroll
        for (int k = 0; k < 4; ++k) {
            int b = cc[k] >> 8;
            p[k] = lbase[b] + atomicAdd(&cnt2[b], 1);
        }
#pragma unroll
        for (int k = 0; k < 4; ++k) {
            int2 v;
            v.x = rr[k] | ((cc[k] & 255) << 20);
            v.y = __float_as_int(w[k]);
            rw[p[k]] = v;
        }
    }
    for (; e < hi; e += stride) {
        int cc = col[e];
        int b = cc >> 8;
        int p = lbase[b] + atomicAdd(&cnt2[b], 1);
        int2 v;
        v.x = row[e] | ((cc & 255) << 20);
        v.y = __float_as_int(ew[e]);
        rw[p] = v;
    }
}

// per-bucket (256 nodes): ONE u64 LDS atomic per edge packs count (bits 63:40)
// and fixed-point (2^-24) weighted degree (bits 39:0). Then LDS scan -> ptr,
// dis; node-sorted scatter (rw2.x = row*32 byte offset); fused xsc build.
__global__ __launch_bounds__(NST) void nodesort_kernel(
        const int2* __restrict__ rw, const int* __restrict__ start,
        const float* __restrict__ x,
        int2* __restrict__ rw2, int* __restrict__ ptr,
        float* __restrict__ dis, __half* __restrict__ xsc,
        int N, int E, int nbuck) {
    __shared__ unsigned long long cd[BS];
    __shared__ int fill[BS];
    __shared__ int stmp[BS];
    __shared__ float sdis[BS];
    int b = blockIdx.x, tid = threadIdx.x;
    if (tid < BS) cd[tid] = 0ull;
    __syncthreads();
    int s0 = start[b], s1 = start[b + 1];

    // pass 1: packed count + weighted degree, 4-way unrolled, 1 atomic/edge
    {
        int e = s0 + tid;
        for (; e + 3 * NST < s1; e += 4 * NST) {
            int2 v[4];
#pragma unroll
            for (int k = 0; k < 4; ++k) v[k] = rw[e + k * NST];
#pragma unroll
            for (int k = 0; k < 4; ++k) {
                int cl = v[k].x >> 20;
                float w = __int_as_float(v[k].y);
                unsigned long long enc =
                    (1ull << 40) | (unsigned long long)(w * 16777216.0f);
                atomicAdd(&cd[cl], enc);
            }
        }
        for (; e < s1; e += NST) {
            int2 v = rw[e];
            int cl = v.x >> 20;
            float w = __int_as_float(v.y);
            unsigned long long enc =
                (1ull << 40) | (unsigned long long)(w * 16777216.0f);
            atomicAdd(&cd[cl], enc);
        }
    }
    __syncthreads();

    // Hillis-Steele inclusive scan of counts in LDS
    int myc = 0;
    if (tid < BS) { myc = (int)(cd[tid] >> 40); stmp[tid] = myc; }
    __syncthreads();
    for (int off = 1; off < BS; off <<= 1) {
        int t = 0;
        if (tid < BS && tid >= off) t = stmp[tid - off];
        __syncthreads();
        if (tid < BS) stmp[tid] += t;
        __syncthreads();
    }
    if (tid < BS) {
        int excl = stmp[tid] - myc;
        ptr[b * BS + tid] = s0 + excl;
        fill[tid] = excl;
        float deg = (float)(cd[tid] & ((1ull << 40) - 1)) * (1.0f / 16777216.0f);
        float d = rsqrtf(deg + 1.0f);
        sdis[tid] = d;
        int node = b * BS + tid;
        if (node < N) dis[node] = d;
    }
    __syncthreads();

    // fused xsc: 4 threads per node, each converts one float4 -> 4 fp16
    {
        int nl = tid >> 2, quad = tid & 3;
        int node = b * BS + nl;
        if (node < N) {
            float d = sdis[nl];
            float4 v = *(const float4*)(x + (size_t)node * 16 + quad * 4);
            __half2 h0 = __floats2half2_rn(v.x * d, v.y * d);
            __half2 h1 = __floats2half2_rn(v.z * d, v.w * d);
            uint2 u;
            u.x = *(unsigned int*)&h0;
            u.y = *(unsigned int*)&h1;
            *(uint2*)(xsc + (size_t)node * 16 + quad * 4) = u;
        }
    }

    // pass 2: scatter to node-sorted order, 4-way unrolled
    {
        int e = s0 + tid;
        for (; e + 3 * NST < s1; e += 4 * NST) {
            int2 v[4];
#pragma unroll
            for (int k = 0; k < 4; ++k) v[k] = rw[e + k * NST];
            int p[4];
#pragma unroll
            for (int k = 0; k < 4; ++k)
                p[k] = s0 + atomicAdd(&fill[v[k].x >> 20], 1);
#pragma unroll
            for (int k = 0; k < 4; ++k) {
                int2 o;
                o.x = (v[k].x & 0xFFFFF) << 5;   // byte offset = row * 32
                o.y = v[k].y;
                rw2[p[k]] = o;
            }
        }
        for (; e < s1; e += NST) {
            int2 v = rw[e];
            int p = s0 + atomicAdd(&fill[v.x >> 20], 1);
            int2 o;
            o.x = (v.x & 0xFFFFF) << 5;
            o.y = v.y;
            rw2[p] = o;
        }
    }
    if (b == 0 && tid == 0) ptr[nbuck * BS] = E;
}

// 4 nodes per wave: lane = grp(4) x slot(4) x quad(4).
// FINAL=0: dst = dis*(agg+self); FINAL=1: dst = dis*(agg+self)+b2.
template <int FINAL>
__global__ __launch_bounds__(256) void gather_kernel(
        const int* __restrict__ ptr, const int2* __restrict__ rw2,
        const __half* __restrict__ src, const float* __restrict__ dis,
        const float* __restrict__ b2, float* __restrict__ dst, int N) {
    int tid  = threadIdx.x;
    int wave = tid >> 6;
    int lane = tid & 63;
    int g = lane >> 4;            // node group within wave
    int s = (lane >> 2) & 3;      // 4 edge slots per node
    int q = lane & 3;             // 4 quads of 4 halves = 16 features
    int node = (blockIdx.x * 4 + wave) * 4 + g;
    if (node >= N) return;
    int s0 = ptr[node], s1 = ptr[node + 1];

    const char* srcb = (const char*)src;
    float4 a0 = {0.f, 0.f, 0.f, 0.f}, a1 = {0.f, 0.f, 0.f, 0.f};
    int e = s0 + s;
    for (; e + 4 < s1; e += 8) {               // 2-way unroll, stride 4/slot
        int2 v0 = nt_load_edge(&rw2[e]);
        int2 v1 = nt_load_edge(&rw2[e + 4]);
        float4 x0 = load_h4((const __half*)(srcb + v0.x) + q * 4);
        float4 x1 = load_h4((const __half*)(srcb + v1.x) + q * 4);
        float w0 = __int_as_float(v0.y), w1 = __int_as_float(v1.y);
        a0.x += w0 * x0.x; a0.y += w0 * x0.y; a0.z += w0 * x0.z; a0.w += w0 * x0.w;
        a1.x += w1 * x1.x; a1.y += w1 * x1.y; a1.z += w1 * x1.z; a1.w += w1 * x1.w;
    }
    if (e < s1) {
        int2 v0 = nt_load_edge(&rw2[e]);
        float4 x0 = load_h4((const __half*)(srcb + v0.x) + q * 4);
        float w0 = __int_as_float(v0.y);
        a0.x += w0 * x0.x; a0.y += w0 * x0.y; a0.z += w0 * x0.z; a0.w += w0 * x0.w;
    }
    a0.x += a1.x; a0.y += a1.y; a0.z += a1.z; a0.w += a1.w;
#pragma unroll
    for (int m = 4; m <= 8; m <<= 1) {         // reduce across 4 slots
        a0.x += __shfl_xor(a0.x, m);
        a0.y += __shfl_xor(a0.y, m);
        a0.z += __shfl_xor(a0.z, m);
        a0.w += __shfl_xor(a0.w, m);
    }

    if (s == 0) {
        float d = dis[node];
        float4 self = load_h4((const __half*)(srcb + ((size_t)node << 5)) + q * 4);
        float4 o;
        o.x = d * (a0.x + self.x);
        o.y = d * (a0.y + self.y);
        o.z = d * (a0.z + self.z);
        o.w = d * (a0.w + self.w);
        if (FINAL) {
            float4 bb = *(const float4*)(b2 + q * 4);
            o.x += bb.x; o.y += bb.y; o.z += bb.z; o.w += bb.w;
        }
        *(float4*)(dst + (size_t)node * 16 + q * 4) = o;
    }
}

// xs2 = fp16((relu(t @ W1^T + b1) @ W2^T) * dis), thread per node, regs only.
__global__ __launch_bounds__(256) void mlp_kernel(
        const float* __restrict__ t, const float* __restrict__ dis,
        const float* __restrict__ W1, const float* __restrict__ b1,
        const float* __restrict__ W2, __half* __restrict__ xs2, int N) {
    __shared__ float sW1[512];
    __shared__ float sW2[512];
    __shared__ float sb1[32];
    for (int k = threadIdx.x; k < 512; k += 256) {
        sW1[k] = W1[k];
        sW2[k] = W2[k];
    }
    if (threadIdx.x < 32) sb1[threadIdx.x] = b1[threadIdx.x];
    __syncthreads();
    int i = blockIdx.x * 256 + threadIdx.x;
    if (i >= N) return;

    float tr[16];
#pragma unroll
    for (int k = 0; k < 4; ++k) {
        float4 v = ((const float4*)(t + (size_t)i * 16))[k];
        tr[4*k+0] = v.x; tr[4*k+1] = v.y; tr[4*k+2] = v.z; tr[4*k+3] = v.w;
    }
    float h[32];
#pragma unroll
    for (int o = 0; o < 32; ++o) {
        float acc = sb1[o];
#pragma unroll
        for (int k = 0; k < 16; ++k) acc += tr[k] * sW1[o * 16 + k];
        h[o] = fmaxf(acc, 0.f);
    }
    float d = dis[i];
    float o16[16];
#pragma unroll
    for (int o = 0; o < 16; ++o) {
        float acc = 0.f;
#pragma unroll
        for (int k = 0; k < 32; ++k) acc += h[k] * sW2[o * 32 + k];
        o16[o] = acc * d;
    }
    __half2 hh[8];
#pragma unroll
    for (int k = 0; k < 8; ++k) hh[k] = __floats2half2_rn(o16[2*k], o16[2*k+1]);
    uint4* dst = (uint4*)(xs2 + (size_t)i * 16);
    dst[0] = *(uint4*)&hh[0];
    dst[1] = *(uint4*)&hh[4];
}

extern "C" void kernel_launch(void* const* d_in, const int* in_sizes, int n_in,
                              void* d_out, int out_size, void* d_ws, size_t ws_size,
                              hipStream_t stream) {
    const float* x  = (const float*)d_in[0];
    const int*   ei = (const int*)d_in[1];   // [2, E] int32
    const float* ew = (const float*)d_in[2];
    const float* W1 = (const float*)d_in[3];
    const float* b1 = (const float*)d_in[4];
    const float* W2 = (const float*)d_in[5];
    const float* b2 = (const float*)d_in[6];
    float* out = (float*)d_out;

    const int N = in_sizes[0] / 16;
    const int E = in_sizes[2];
    const int* row = ei;
    const int* col = ei + E;

    const int nbuck = (N + BS - 1) / BS;          // 391
    const int per   = (E + CHUNKS - 1) / CHUNKS;  // 12500

    // workspace layout (4B units)
    //  [0, 2E)   : rw2 (node-sorted int2, .x = byte offset)
    //  [2E, 4E)  : rw (bucket-sorted int2), DEAD after nodesort; reused:
    //              xsc half[16N] (8N units) at 2E
    //              tbuf f32[16N] (16N units) at 2E+8N
    //              xs2 half[16N] (8N units) at 2E+24N      (32N <= 2E ok)
    //  [4E, ...) : dis[N], ptr[BS*nbuck+1], part, base, tot, start
    //  NOTE: xsc is written by nodesort (fused) while rw is still live --
    //  xsc occupies [2E, 2E+8N) and nodesort reads rw from [2E, 4E)... they
    //  would overlap, so move xsc to AFTER the int arrays instead.
    float*  ws    = (float*)d_ws;
    int2*   rw2   = (int2*)ws;
    int2*   rw    = (int2*)(ws + (size_t)2 * E);
    float*  tbuf  = ws + (size_t)2 * E;                     // reuses rw region
    __half* xs2   = (__half*)(ws + (size_t)2 * E + (size_t)16 * N);
    float*  dis   = ws + (size_t)4 * E;
    int*    ptr   = (int*)(dis + N);
    int*    part  = ptr + (size_t)BS * nbuck + 1;
    int*    base  = part + (size_t)CHUNKS * nbuck;
    int*    tot   = base + (size_t)CHUNKS * nbuck;
    int*    start = tot + nbuck;
    __half* xsc   = (__half*)(start + nbuck + 1);           // 8N units, outside rw

    hist_kernel<<<CHUNKS, 1024, nbuck * 4, stream>>>(col, part, E, nbuck, per);
    colscan_kernel<<<nbuck, 64, 0, stream>>>(part, base, tot, nbuck);
    bscan_kernel<<<1, 512, 0, stream>>>(tot, start, nbuck, E);
    place_kernel<<<CHUNKS, 1024, 2 * nbuck * 4, stream>>>(row, col, ew, start, base, rw, E, nbuck, per);
    nodesort_kernel<<<nbuck, NST, 0, stream>>>(rw, start, x, rw2, ptr, dis, xsc, N, E, nbuck);

    {
        int gblocks = (N + 15) / 16;   // 16 nodes per 256-thread block
        gather_kernel<0><<<gblocks, 256, 0, stream>>>(ptr, rw2, xsc, dis, b2, tbuf, N);
        mlp_kernel<<<(N + 255) / 256, 256, 0, stream>>>(tbuf, dis, W1, b1, W2, xs2, N);
        gather_kernel<1><<<gblocks, 256, 0, stream>>>(ptr, rw2, xs2, dis, b2, out, N);
    }
}

// Round 20
// 160.343 us; speedup vs baseline: 1.1677x; 1.0131x over previous
//
#include <hip/hip_runtime.h>
#include <hip/hip_fp16.h>
#include <cstdint>

// ---------------------------------------------------------------------------
// 2-layer GCN, zero scattered global atomics, per-node CSR gather.
// Gather tables (xsc, xs2) are fp16 [N,16] = 3.2 MB (L2-resident).
// Gathers: 4 nodes per wave, lane = grp(4)x slot(4)x quad(4), 4-way unroll
// (4 independent edge->table chains per lane for latency hiding).
// CSR build: hist / colscan / bscan / place (4-way ILP) / nodesort
// (packed u64 LDS atomic: count<<40 | fixed-point deg; fused xsc build).
// ---------------------------------------------------------------------------

#define BS 256          // nodes per bucket (CSR build)
#define CHUNKS 256      // edge chunks for hist/place
#define NST 1024        // nodesort threads per block

__device__ __forceinline__ int2 nt_load_edge(const int2* p) {
    long long v = __builtin_nontemporal_load((const long long*)p);
    int2 r;
    r.x = (int)(v & 0xFFFFFFFFll);
    r.y = (int)(v >> 32);
    return r;
}

// 4 fp16 -> 4 fp32 from an 8B-aligned half pointer
__device__ __forceinline__ float4 load_h4(const __half* p) {
    uint2 u = *(const uint2*)p;
    __half2 p0 = *(__half2*)&u.x;
    __half2 p1 = *(__half2*)&u.y;
    float2 f0 = __half22float2(p0);
    float2 f1 = __half22float2(p1);
    float4 r;
    r.x = f0.x; r.y = f0.y; r.z = f1.x; r.w = f1.y;
    return r;
}

__global__ __launch_bounds__(1024) void hist_kernel(
        const int* __restrict__ col, int* __restrict__ part,
        int E, int nbuck, int per) {
    extern __shared__ int sh[];
    for (int t = threadIdx.x; t < nbuck; t += blockDim.x) sh[t] = 0;
    __syncthreads();
    int lo = blockIdx.x * per, hi = min(E, lo + per);
    for (int e = lo + threadIdx.x; e < hi; e += blockDim.x)
        atomicAdd(&sh[col[e] >> 8], 1);
    __syncthreads();
    for (int t = threadIdx.x; t < nbuck; t += blockDim.x)
        part[(size_t)blockIdx.x * nbuck + t] = sh[t];
}

__global__ void colscan_kernel(const int* __restrict__ part, int* __restrict__ base,
                               int* __restrict__ tot, int nbuck) {
    int b = blockIdx.x;
    if (b >= nbuck) return;
    int lane = threadIdx.x;  // 64
    int off = 0;
    for (int g = 0; g < CHUNKS; g += 64) {
        int c = g + lane;
        int v = part[(size_t)c * nbuck + b];
        int s = v;
        #pragma unroll
        for (int d = 1; d < 64; d <<= 1) {
            int t = __shfl_up(s, d);
            if (lane >= d) s += t;
        }
        base[(size_t)c * nbuck + b] = off + (s - v);
        off += __shfl(s, 63);
    }
    if (lane == 0) tot[b] = off;
}

// single-block exclusive scan of tot[nbuck] -> start[nbuck+1] (nbuck <= 512)
__global__ void bscan_kernel(const int* __restrict__ tot, int* __restrict__ start,
                             int nbuck, int E) {
    __shared__ int s[512];
    int tid = threadIdx.x;
    int v = (tid < nbuck) ? tot[tid] : 0;
    s[tid] = v;
    __syncthreads();
    for (int off = 1; off < 512; off <<= 1) {
        int t = (tid >= off) ? s[tid - off] : 0;
        __syncthreads();
        s[tid] += t;
        __syncthreads();
    }
    if (tid < nbuck) start[tid] = s[tid] - v;
    if (tid == 0) start[nbuck] = E;
}

// 4-way ILP: 4 independent load->LDS-atomic->store chains in flight per thread
__global__ __launch_bounds__(1024) void place_kernel(
        const int* __restrict__ row, const int* __restrict__ col,
        const float* __restrict__ ew,
        const int* __restrict__ start, const int* __restrict__ base,
        int2* __restrict__ rw, int E, int nbuck, int per) {
    extern __shared__ int sh[];
    int* lbase = sh;          // nbuck
    int* cnt2  = sh + nbuck;  // nbuck
    int c = blockIdx.x;
    for (int t = threadIdx.x; t < nbuck; t += blockDim.x) {
        lbase[t] = start[t] + base[(size_t)c * nbuck + t];
        cnt2[t] = 0;
    }
    __syncthreads();
    int lo = c * per, hi = min(E, lo + per);
    const int stride = blockDim.x;
    int e = lo + threadIdx.x;
    for (; e + 3 * stride < hi; e += 4 * stride) {
        int cc[4], rr[4];
        float w[4];
#pragma unroll
        for (int k = 0; k < 4; ++k) {
            cc[k] = col[e + k * stride];
            rr[k] = row[e + k * stride];
            w[k]  = ew[e + k * stride];
        }
        int p[4];
#pragma unroll
        for (int k = 0; k < 4; ++k) {
            int b = cc[k] >> 8;
            p[k] = lbase[b] + atomicAdd(&cnt2[b], 1);
        }
#pragma unroll
        for (int k = 0; k < 4; ++k) {
            int2 v;
            v.x = rr[k] | ((cc[k] & 255) << 20);
            v.y = __float_as_int(w[k]);
            rw[p[k]] = v;
        }
    }
    for (; e < hi; e += stride) {
        int cc = col[e];
        int b = cc >> 8;
        int p = lbase[b] + atomicAdd(&cnt2[b], 1);
        int2 v;
        v.x = row[e] | ((cc & 255) << 20);
        v.y = __float_as_int(ew[e]);
        rw[p] = v;
    }
}

// per-bucket (256 nodes): ONE u64 LDS atomic per edge packs count (bits 63:40)
// and fixed-point (2^-24) weighted degree (bits 39:0). Then LDS scan -> ptr,
// dis; node-sorted scatter (rw2.x = row*32 byte offset); fused xsc build.
__global__ __launch_bounds__(NST) void nodesort_kernel(
        const int2* __restrict__ rw, const int* __restrict__ start,
        const float* __restrict__ x,
        int2* __restrict__ rw2, int* __restrict__ ptr,
        float* __restrict__ dis, __half* __restrict__ xsc,
        int N, int E, int nbuck) {
    __shared__ unsigned long long cd[BS];
    __shared__ int fill[BS];
    __shared__ int stmp[BS];
    __shared__ float sdis[BS];
    int b = blockIdx.x, tid = threadIdx.x;
    if (tid < BS) cd[tid] = 0ull;
    __syncthreads();
    int s0 = start[b], s1 = start[b + 1];

    // pass 1: packed count + weighted degree, 4-way unrolled, 1 atomic/edge
    {
        int e = s0 + tid;
        for (; e + 3 * NST < s1; e += 4 * NST) {
            int2 v[4];
#pragma unroll
            for (int k = 0; k < 4; ++k) v[k] = rw[e + k * NST];
#pragma unroll
            for (int k = 0; k < 4; ++k) {
                int cl = v[k].x >> 20;
                float w = __int_as_float(v[k].y);
                unsigned long long enc =
                    (1ull << 40) | (unsigned long long)(w * 16777216.0f);
                atomicAdd(&cd[cl], enc);
            }
        }
        for (; e < s1; e += NST) {
            int2 v = rw[e];
            int cl = v.x >> 20;
            float w = __int_as_float(v.y);
            unsigned long long enc =
                (1ull << 40) | (unsigned long long)(w * 16777216.0f);
            atomicAdd(&cd[cl], enc);
        }
    }
    __syncthreads();

    // Hillis-Steele inclusive scan of counts in LDS
    int myc = 0;
    if (tid < BS) { myc = (int)(cd[tid] >> 40); stmp[tid] = myc; }
    __syncthreads();
    for (int off = 1; off < BS; off <<= 1) {
        int t = 0;
        if (tid < BS && tid >= off) t = stmp[tid - off];
        __syncthreads();
        if (tid < BS) stmp[tid] += t;
        __syncthreads();
    }
    if (tid < BS) {
        int excl = stmp[tid] - myc;
        ptr[b * BS + tid] = s0 + excl;
        fill[tid] = excl;
        float deg = (float)(cd[tid] & ((1ull << 40) - 1)) * (1.0f / 16777216.0f);
        float d = rsqrtf(deg + 1.0f);
        sdis[tid] = d;
        int node = b * BS + tid;
        if (node < N) dis[node] = d;
    }
    __syncthreads();

    // fused xsc: 4 threads per node, each converts one float4 -> 4 fp16
    {
        int nl = tid >> 2, quad = tid & 3;
        int node = b * BS + nl;
        if (node < N) {
            float d = sdis[nl];
            float4 v = *(const float4*)(x + (size_t)node * 16 + quad * 4);
            __half2 h0 = __floats2half2_rn(v.x * d, v.y * d);
            __half2 h1 = __floats2half2_rn(v.z * d, v.w * d);
            uint2 u;
            u.x = *(unsigned int*)&h0;
            u.y = *(unsigned int*)&h1;
            *(uint2*)(xsc + (size_t)node * 16 + quad * 4) = u;
        }
    }

    // pass 2: scatter to node-sorted order, 4-way unrolled
    {
        int e = s0 + tid;
        for (; e + 3 * NST < s1; e += 4 * NST) {
            int2 v[4];
#pragma unroll
            for (int k = 0; k < 4; ++k) v[k] = rw[e + k * NST];
            int p[4];
#pragma unroll
            for (int k = 0; k < 4; ++k)
                p[k] = s0 + atomicAdd(&fill[v[k].x >> 20], 1);
#pragma unroll
            for (int k = 0; k < 4; ++k) {
                int2 o;
                o.x = (v[k].x & 0xFFFFF) << 5;   // byte offset = row * 32
                o.y = v[k].y;
                rw2[p[k]] = o;
            }
        }
        for (; e < s1; e += NST) {
            int2 v = rw[e];
            int p = s0 + atomicAdd(&fill[v.x >> 20], 1);
            int2 o;
            o.x = (v.x & 0xFFFFF) << 5;
            o.y = v.y;
            rw2[p] = o;
        }
    }
    if (b == 0 && tid == 0) ptr[nbuck * BS] = E;
}

// 4 nodes per wave: lane = grp(4) x slot(4) x quad(4); 4-way unrolled main
// loop (4 independent edge->table chains per lane).
// FINAL=0: dst = dis*(agg+self); FINAL=1: dst = dis*(agg+self)+b2.
template <int FINAL>
__global__ __launch_bounds__(256) void gather_kernel(
        const int* __restrict__ ptr, const int2* __restrict__ rw2,
        const __half* __restrict__ src, const float* __restrict__ dis,
        const float* __restrict__ b2, float* __restrict__ dst, int N) {
    int tid  = threadIdx.x;
    int wave = tid >> 6;
    int lane = tid & 63;
    int g = lane >> 4;            // node group within wave
    int s = (lane >> 2) & 3;      // 4 edge slots per node
    int q = lane & 3;             // 4 quads of 4 halves = 16 features
    int node = (blockIdx.x * 4 + wave) * 4 + g;
    if (node >= N) return;
    int s0 = ptr[node], s1 = ptr[node + 1];

    const char* srcb = (const char*)src;
    float4 a0 = {0.f, 0.f, 0.f, 0.f}, a1 = {0.f, 0.f, 0.f, 0.f};
    float4 a2 = {0.f, 0.f, 0.f, 0.f}, a3 = {0.f, 0.f, 0.f, 0.f};
    int e = s0 + s;
    for (; e + 12 < s1; e += 16) {             // 4-way unroll, stride 4/slot
        int2 v0 = nt_load_edge(&rw2[e]);
        int2 v1 = nt_load_edge(&rw2[e + 4]);
        int2 v2 = nt_load_edge(&rw2[e + 8]);
        int2 v3 = nt_load_edge(&rw2[e + 12]);
        float4 x0 = load_h4((const __half*)(srcb + v0.x) + q * 4);
        float4 x1 = load_h4((const __half*)(srcb + v1.x) + q * 4);
        float4 x2 = load_h4((const __half*)(srcb + v2.x) + q * 4);
        float4 x3 = load_h4((const __half*)(srcb + v3.x) + q * 4);
        float w0 = __int_as_float(v0.y), w1 = __int_as_float(v1.y);
        float w2 = __int_as_float(v2.y), w3 = __int_as_float(v3.y);
        a0.x += w0 * x0.x; a0.y += w0 * x0.y; a0.z += w0 * x0.z; a0.w += w0 * x0.w;
        a1.x += w1 * x1.x; a1.y += w1 * x1.y; a1.z += w1 * x1.z; a1.w += w1 * x1.w;
        a2.x += w2 * x2.x; a2.y += w2 * x2.y; a2.z += w2 * x2.z; a2.w += w2 * x2.w;
        a3.x += w3 * x3.x; a3.y += w3 * x3.y; a3.z += w3 * x3.z; a3.w += w3 * x3.w;
    }
    for (; e < s1; e += 4) {                   // remainder (<= 3 per slot)
        int2 v0 = nt_load_edge(&rw2[e]);
        float4 x0 = load_h4((const __half*)(srcb + v0.x) + q * 4);
        float w0 = __int_as_float(v0.y);
        a0.x += w0 * x0.x; a0.y += w0 * x0.y; a0.z += w0 * x0.z; a0.w += w0 * x0.w;
    }
    a0.x += a1.x; a0.y += a1.y; a0.z += a1.z; a0.w += a1.w;
    a2.x += a3.x; a2.y += a3.y; a2.z += a3.z; a2.w += a3.w;
    a0.x += a2.x; a0.y += a2.y; a0.z += a2.z; a0.w += a2.w;
#pragma unroll
    for (int m = 4; m <= 8; m <<= 1) {         // reduce across 4 slots
        a0.x += __shfl_xor(a0.x, m);
        a0.y += __shfl_xor(a0.y, m);
        a0.z += __shfl_xor(a0.z, m);
        a0.w += __shfl_xor(a0.w, m);
    }

    if (s == 0) {
        float d = dis[node];
        float4 self = load_h4((const __half*)(srcb + ((size_t)node << 5)) + q * 4);
        float4 o;
        o.x = d * (a0.x + self.x);
        o.y = d * (a0.y + self.y);
        o.z = d * (a0.z + self.z);
        o.w = d * (a0.w + self.w);
        if (FINAL) {
            float4 bb = *(const float4*)(b2 + q * 4);
            o.x += bb.x; o.y += bb.y; o.z += bb.z; o.w += bb.w;
        }
        *(float4*)(dst + (size_t)node * 16 + q * 4) = o;
    }
}

// xs2 = fp16((relu(t @ W1^T + b1) @ W2^T) * dis), thread per node, regs only.
__global__ __launch_bounds__(256) void mlp_kernel(
        const float* __restrict__ t, const float* __restrict__ dis,
        const float* __restrict__ W1, const float* __restrict__ b1,
        const float* __restrict__ W2, __half* __restrict__ xs2, int N) {
    __shared__ float sW1[512];
    __shared__ float sW2[512];
    __shared__ float sb1[32];
    for (int k = threadIdx.x; k < 512; k += 256) {
        sW1[k] = W1[k];
        sW2[k] = W2[k];
    }
    if (threadIdx.x < 32) sb1[threadIdx.x] = b1[threadIdx.x];
    __syncthreads();
    int i = blockIdx.x * 256 + threadIdx.x;
    if (i >= N) return;

    float tr[16];
#pragma unroll
    for (int k = 0; k < 4; ++k) {
        float4 v = ((const float4*)(t + (size_t)i * 16))[k];
        tr[4*k+0] = v.x; tr[4*k+1] = v.y; tr[4*k+2] = v.z; tr[4*k+3] = v.w;
    }
    float h[32];
#pragma unroll
    for (int o = 0; o < 32; ++o) {
        float acc = sb1[o];
#pragma unroll
        for (int k = 0; k < 16; ++k) acc += tr[k] * sW1[o * 16 + k];
        h[o] = fmaxf(acc, 0.f);
    }
    float d = dis[i];
    float o16[16];
#pragma unroll
    for (int o = 0; o < 16; ++o) {
        float acc = 0.f;
#pragma unroll
        for (int k = 0; k < 32; ++k) acc += h[k] * sW2[o * 32 + k];
        o16[o] = acc * d;
    }
    __half2 hh[8];
#pragma unroll
    for (int k = 0; k < 8; ++k) hh[k] = __floats2half2_rn(o16[2*k], o16[2*k+1]);
    uint4* dst = (uint4*)(xs2 + (size_t)i * 16);
    dst[0] = *(uint4*)&hh[0];
    dst[1] = *(uint4*)&hh[4];
}

extern "C" void kernel_launch(void* const* d_in, const int* in_sizes, int n_in,
                              void* d_out, int out_size, void* d_ws, size_t ws_size,
                              hipStream_t stream) {
    const float* x  = (const float*)d_in[0];
    const int*   ei = (const int*)d_in[1];   // [2, E] int32
    const float* ew = (const float*)d_in[2];
    const float* W1 = (const float*)d_in[3];
    const float* b1 = (const float*)d_in[4];
    const float* W2 = (const float*)d_in[5];
    const float* b2 = (const float*)d_in[6];
    float* out = (float*)d_out;

    const int N = in_sizes[0] / 16;
    const int E = in_sizes[2];
    const int* row = ei;
    const int* col = ei + E;

    const int nbuck = (N + BS - 1) / BS;          // 391
    const int per   = (E + CHUNKS - 1) / CHUNKS;  // 12500

    // workspace layout (4B units)
    //  [0, 2E)   : rw2 (node-sorted int2, .x = byte offset)
    //  [2E, 4E)  : rw (bucket-sorted int2), DEAD after nodesort; reused:
    //              tbuf f32[16N] at 2E, xs2 half[16N] at 2E+16N
    //  [4E, ...) : dis[N], ptr[BS*nbuck+1], part, base, tot, start,
    //              xsc half[16N] (outside rw -- written while rw is live)
    float*  ws    = (float*)d_ws;
    int2*   rw2   = (int2*)ws;
    int2*   rw    = (int2*)(ws + (size_t)2 * E);
    float*  tbuf  = ws + (size_t)2 * E;                     // reuses rw region
    __half* xs2   = (__half*)(ws + (size_t)2 * E + (size_t)16 * N);
    float*  dis   = ws + (size_t)4 * E;
    int*    ptr   = (int*)(dis + N);
    int*    part  = ptr + (size_t)BS * nbuck + 1;
    int*    base  = part + (size_t)CHUNKS * nbuck;
    int*    tot   = base + (size_t)CHUNKS * nbuck;
    int*    start = tot + nbuck;
    __half* xsc   = (__half*)(start + nbuck + 1);           // 8N units, outside rw

    hist_kernel<<<CHUNKS, 1024, nbuck * 4, stream>>>(col, part, E, nbuck, per);
    colscan_kernel<<<nbuck, 64, 0, stream>>>(part, base, tot, nbuck);
    bscan_kernel<<<1, 512, 0, stream>>>(tot, start, nbuck, E);
    place_kernel<<<CHUNKS, 1024, 2 * nbuck * 4, stream>>>(row, col, ew, start, base, rw, E, nbuck, per);
    nodesort_kernel<<<nbuck, NST, 0, stream>>>(rw, start, x, rw2, ptr, dis, xsc, N, E, nbuck);

    {
        int gblocks = (N + 15) / 16;   // 16 nodes per 256-thread block
        gather_kernel<0><<<gblocks, 256, 0, stream>>>(ptr, rw2, xsc, dis, b2, tbuf, N);
        mlp_kernel<<<(N + 255) / 256, 256, 0, stream>>>(tbuf, dis, W1, b1, W2, xs2, N);
        gather_kernel<1><<<gblocks, 256, 0, stream>>>(ptr, rw2, xs2, dis, b2, out, N);
    }
}